// Round 4
// baseline (412.755 us; speedup 1.0000x reference)
//
#include <hip/hip_runtime.h>
#include <hip/hip_bf16.h>

typedef __attribute__((ext_vector_type(8))) short bf16x8;
typedef __attribute__((ext_vector_type(4))) float f32x4;

#define EPSV 1e-4f

static __device__ __forceinline__ unsigned short f2bf(float f) {
    unsigned int u = __builtin_bit_cast(unsigned int, f);
    u += 0x7FFFu + ((u >> 16) & 1u);   // round-to-nearest-even
    return (unsigned short)(u >> 16);
}
static __device__ __forceinline__ float bf2f(unsigned short u) {
    unsigned int x = ((unsigned int)u) << 16;
    return __builtin_bit_cast(float, x);
}

// ---------------- x (fp32) -> bf16 ----------------
__global__ __launch_bounds__(256) void k_cvt_bf16(
    const float* __restrict__ in, unsigned short* __restrict__ out, long n4) {
    long i0 = (long)blockIdx.x * 256 + threadIdx.x;
    long stride = (long)gridDim.x * 256;
    const float4* in4 = (const float4*)in;
    ushort4* out4 = (ushort4*)out;
    for (long i = i0; i < n4; i += stride) {
        float4 v = in4[i];
        ushort4 o;
        o.x = f2bf(v.x); o.y = f2bf(v.y); o.z = f2bf(v.z); o.w = f2bf(v.w);
        out4[i] = o;
    }
}

// ---------------- pack W[k][c][d] (fp32) into MFMA-fragment-ordered bf16 ----------------
// frag f = k*8 + s*4 + t ; lane l holds B[k=32s+(l>>4)*8+j][col=16t+(l&15)], j=0..7
__global__ __launch_bounds__(256) void k_pack_w(
    const float* __restrict__ w, unsigned short* __restrict__ P) {
    int tid = blockIdx.x * 256 + threadIdx.x;
    if (tid >= 9 * 8 * 64) return;
    int lane = tid & 63;
    int f = tid >> 6;
    int t = f & 3, s = (f >> 2) & 1, k = f >> 3;
    int d = (t << 4) + (lane & 15);
    int c0 = (s << 5) + ((lane >> 4) << 3);
    bf16x8 v;
#pragma unroll
    for (int j = 0; j < 8; ++j)
        v[j] = (short)f2bf(w[((k * 64) + c0 + j) * 64 + d]);
    ((bf16x8*)P)[tid] = v;
}

// ---------------- gather-GEMM conv: out[n,d] = sum_k sum_c X[nbr[n,k],c] * W[k,c,d] ----------------
// 512 threads = 8 waves; wave owns 32 rows (two 16-row MFMA tiles); block = 256 rows.
// B from LDS (ds_read pipe), staged in TWO 40 KB stages (k=0..4, k=5..8) so LDS = 40 KB
// -> 3 blocks/CU = 24 waves/CU. Depth-2 A-gather pipeline runs across both stages.
__global__ __launch_bounds__(512, 6) void k_conv(
    const unsigned short* __restrict__ Xb,   // bf16 features [n][64]
    const int* __restrict__ nbr,             // [n][9]
    const unsigned short* __restrict__ P,    // packed weights (bf16, 9*8 frags)
    unsigned short* __restrict__ outb,       // bf16 out
    float* __restrict__ partials,            // [nblocks][128] sum/sumsq partials
    int n) {
    __shared__ unsigned short sB[20480];     // 40 KB: up to 5 offsets' fragments
    const int tid = threadIdx.x;
    const int w = tid >> 6, l = tid & 63;
    const int rl = l & 15, ch = l >> 4;
    const int bm = blockIdx.x * 256 + (w << 5);
    const bool valid = bm < n;               // n % 32 == 0 -> wave-uniform
    const int r0 = valid ? bm + rl : 0;
    const int r1 = valid ? bm + 16 + rl : 0;

    {   // stage 1: offsets k=0..4 (2560 float4)
        const float4* src = (const float4*)P;
        float4* dst = (float4*)sB;
#pragma unroll
        for (int i = 0; i < 5; ++i) dst[i * 512 + tid] = src[i * 512 + tid];
    }

    int idx0[9], idx1[9];
#pragma unroll
    for (int k = 0; k < 9; ++k) {
        idx0[k] = nbr[(long)r0 * 9 + k];
        idx1[k] = nbr[(long)r1 * 9 + k];
    }

    const bf16x8* __restrict__ Xv = (const bf16x8*)Xb;
    f32x4 acc0[4] = {}, acc1[4] = {};

    // A-gather pipeline, depth 2
    bf16x8 a[2][4];
#pragma unroll
    for (int d = 0; d < 2; ++d) {
        long i0 = (long)idx0[d] * 8, i1 = (long)idx1[d] * 8;
        a[d][0] = Xv[i0 + ch];     a[d][1] = Xv[i0 + 4 + ch];
        a[d][2] = Xv[i1 + ch];     a[d][3] = Xv[i1 + 4 + ch];
    }

    __syncthreads();   // stage 1 ready

    const bf16x8* Bv = (const bf16x8*)sB;
#pragma unroll
    for (int k = 0; k < 5; ++k) {
        bf16x8 c0 = a[k & 1][0], c1 = a[k & 1][1];
        bf16x8 c2 = a[k & 1][2], c3 = a[k & 1][3];
        if (k < 7) {   // prefetch A for k+2
            long j0 = (long)idx0[k + 2] * 8, j1 = (long)idx1[k + 2] * 8;
            a[k & 1][0] = Xv[j0 + ch];     a[k & 1][1] = Xv[j0 + 4 + ch];
            a[k & 1][2] = Xv[j1 + ch];     a[k & 1][3] = Xv[j1 + 4 + ch];
        }
#pragma unroll
        for (int t = 0; t < 4; ++t) {
            bf16x8 b0 = Bv[(k * 8 + t) * 64 + l];
            bf16x8 b1 = Bv[(k * 8 + 4 + t) * 64 + l];
            acc0[t] = __builtin_amdgcn_mfma_f32_16x16x32_bf16(c0, b0, acc0[t], 0, 0, 0);
            acc0[t] = __builtin_amdgcn_mfma_f32_16x16x32_bf16(c1, b1, acc0[t], 0, 0, 0);
            acc1[t] = __builtin_amdgcn_mfma_f32_16x16x32_bf16(c2, b0, acc1[t], 0, 0, 0);
            acc1[t] = __builtin_amdgcn_mfma_f32_16x16x32_bf16(c3, b1, acc1[t], 0, 0, 0);
        }
    }

    __syncthreads();   // all stage-1 reads done
    {   // stage 2: offsets k=5..8 (2048 float4)
        const float4* src = (const float4*)P;
        float4* dst = (float4*)sB;
#pragma unroll
        for (int i = 0; i < 4; ++i) dst[i * 512 + tid] = src[2560 + i * 512 + tid];
    }
    __syncthreads();   // stage 2 ready

#pragma unroll
    for (int k = 5; k < 9; ++k) {
        bf16x8 c0 = a[k & 1][0], c1 = a[k & 1][1];
        bf16x8 c2 = a[k & 1][2], c3 = a[k & 1][3];
        if (k < 7) {   // prefetch A for k+2
            long j0 = (long)idx0[k + 2] * 8, j1 = (long)idx1[k + 2] * 8;
            a[k & 1][0] = Xv[j0 + ch];     a[k & 1][1] = Xv[j0 + 4 + ch];
            a[k & 1][2] = Xv[j1 + ch];     a[k & 1][3] = Xv[j1 + 4 + ch];
        }
        const int kk = k - 5;
#pragma unroll
        for (int t = 0; t < 4; ++t) {
            bf16x8 b0 = Bv[(kk * 8 + t) * 64 + l];
            bf16x8 b1 = Bv[(kk * 8 + 4 + t) * 64 + l];
            acc0[t] = __builtin_amdgcn_mfma_f32_16x16x32_bf16(c0, b0, acc0[t], 0, 0, 0);
            acc0[t] = __builtin_amdgcn_mfma_f32_16x16x32_bf16(c1, b1, acc0[t], 0, 0, 0);
            acc1[t] = __builtin_amdgcn_mfma_f32_16x16x32_bf16(c2, b0, acc1[t], 0, 0, 0);
            acc1[t] = __builtin_amdgcn_mfma_f32_16x16x32_bf16(c3, b1, acc1[t], 0, 0, 0);
        }
    }

    // C/D layout: col = 16t + rl, row = ch*4 + reg  (tile1 rows +16)
    if (valid) {
#pragma unroll
        for (int t = 0; t < 4; ++t)
#pragma unroll
            for (int r = 0; r < 4; ++r) {
                outb[(long)(bm + (ch << 2) + r) * 64 + (t << 4) + rl] = f2bf(acc0[t][r]);
                outb[(long)(bm + 16 + (ch << 2) + r) * 64 + (t << 4) + rl] = f2bf(acc1[t][r]);
            }
    }

    // per-block BN stat partials (exact fp32 from accumulators)
    float sa[4], sq[4];
#pragma unroll
    for (int t = 0; t < 4; ++t) {
        float s = 0.f, q = 0.f;
#pragma unroll
        for (int r = 0; r < 4; ++r) {
            s += acc0[t][r] + acc1[t][r];
            q += acc0[t][r] * acc0[t][r] + acc1[t][r] * acc1[t][r];
        }
        s += __shfl_xor(s, 16); s += __shfl_xor(s, 32);
        q += __shfl_xor(q, 16); q += __shfl_xor(q, 32);
        sa[t] = valid ? s : 0.f;
        sq[t] = valid ? q : 0.f;
    }
    __syncthreads();   // all LDS B reads done -> safe to overlay stats on sB
    float* sStat = (float*)sB;   // [8][128]
    if (l < 16) {
#pragma unroll
        for (int t = 0; t < 4; ++t) {
            sStat[w * 128 + (t << 4) + l] = sa[t];
            sStat[w * 128 + 64 + (t << 4) + l] = sq[t];
        }
    }
    __syncthreads();
    if (tid < 128) {
        float s = 0.f;
#pragma unroll
        for (int i = 0; i < 8; ++i) s += sStat[i * 128 + tid];
        partials[(long)blockIdx.x * 128 + tid] = s;
    }
}

// ---------------- reduce partials -> scale/shift ----------------
__global__ __launch_bounds__(256) void k_bnstats(
    const float* __restrict__ partials, int nb, int n,
    const float* __restrict__ gamma, const float* __restrict__ beta,
    float* __restrict__ ss) {
    const int d = blockIdx.x;     // 0..63
    const int tid = threadIdx.x;
    float s = 0.f, q = 0.f;
    for (int i = tid; i < nb; i += 256) {
        s += partials[(long)i * 128 + d];
        q += partials[(long)i * 128 + 64 + d];
    }
#pragma unroll
    for (int off = 32; off > 0; off >>= 1) {
        s += __shfl_xor(s, off);
        q += __shfl_xor(q, off);
    }
    __shared__ float rs_[4], rq_[4];
    if ((tid & 63) == 0) { rs_[tid >> 6] = s; rq_[tid >> 6] = q; }
    __syncthreads();
    if (tid == 0) {
        s = rs_[0] + rs_[1] + rs_[2] + rs_[3];
        q = rq_[0] + rq_[1] + rq_[2] + rq_[3];
        float mu = s / (float)n;
        float var = q / (float)n - mu * mu;
        float rsg = rsqrtf(var + EPSV);
        float sc = rsg * gamma[d];
        ss[d] = sc;
        ss[64 + d] = beta[d] - mu * sc;
    }
}

// ---------------- BN1 + ReLU -> bf16 h ----------------
__global__ __launch_bounds__(256) void k_bnrelu(
    const unsigned short* __restrict__ in, const float* __restrict__ ss,
    unsigned short* __restrict__ outb, long n8) {
    __shared__ float ssc[64], ssh[64];
    if (threadIdx.x < 64) { ssc[threadIdx.x] = ss[threadIdx.x]; ssh[threadIdx.x] = ss[64 + threadIdx.x]; }
    __syncthreads();
    long i0 = (long)blockIdx.x * 256 + threadIdx.x;
    long stride = (long)gridDim.x * 256;
    const bf16x8* in8 = (const bf16x8*)in;
    bf16x8* o8 = (bf16x8*)outb;
    for (long i = i0; i < n8; i += stride) {
        bf16x8 v = in8[i];
        int db = (int)((i & 7) << 3);
        bf16x8 o;
#pragma unroll
        for (int j = 0; j < 8; ++j) {
            float f = bf2f((unsigned short)v[j]);
            f = fmaxf(f * ssc[db + j] + ssh[db + j], 0.f);
            o[j] = (short)f2bf(f);
        }
        o8[i] = o;
    }
}

// ---------------- BN2 + residual + ReLU: out = relu(bn2(conv2_bf16) + x_bf16) ----------------
__global__ __launch_bounds__(256) void k_final(
    float* __restrict__ out, const unsigned short* __restrict__ xb,
    const unsigned short* __restrict__ c2, const float* __restrict__ ss, long n4) {
    __shared__ float ssc[64], ssh[64];
    if (threadIdx.x < 64) { ssc[threadIdx.x] = ss[threadIdx.x]; ssh[threadIdx.x] = ss[64 + threadIdx.x]; }
    __syncthreads();
    long i0 = (long)blockIdx.x * 256 + threadIdx.x;
    long stride = (long)gridDim.x * 256;
    const ushort4* x4 = (const ushort4*)xb;
    const ushort4* c4 = (const ushort4*)c2;
    float4* o4 = (float4*)out;
    for (long i = i0; i < n4; i += stride) {
        ushort4 v = c4[i];
        ushort4 xv = x4[i];
        int db = (int)((i & 15) << 2);
        float4 r;
        r.x = fmaxf(bf2f(v.x) * ssc[db + 0] + ssh[db + 0] + bf2f(xv.x), 0.f);
        r.y = fmaxf(bf2f(v.y) * ssc[db + 1] + ssh[db + 1] + bf2f(xv.y), 0.f);
        r.z = fmaxf(bf2f(v.z) * ssc[db + 2] + ssh[db + 2] + bf2f(xv.z), 0.f);
        r.w = fmaxf(bf2f(v.w) * ssc[db + 3] + ssh[db + 3] + bf2f(xv.w), 0.f);
        o4[i] = r;
    }
}

extern "C" void kernel_launch(void* const* d_in, const int* in_sizes, int n_in,
                              void* d_out, int out_size, void* d_ws, size_t ws_size,
                              hipStream_t stream) {
    const float* x  = (const float*)d_in[0];
    const int* nbr  = (const int*)d_in[1];
    const float* w1 = (const float*)d_in[2];
    const float* w2 = (const float*)d_in[3];
    const float* g1 = (const float*)d_in[4];
    const float* b1 = (const float*)d_in[5];
    const float* g2 = (const float*)d_in[6];
    const float* b2 = (const float*)d_in[7];
    float* out = (float*)d_out;

    const int n = in_sizes[0] / 64;          // 500000
    const int nbc = (n + 255) / 256;         // conv blocks (256 rows each)
    const long n64 = (long)n * 64;

    char* ws = (char*)d_ws;
    size_t off = 0;
    auto take = [&](size_t bytes) {
        char* p = ws + off;
        off = (off + bytes + 255) & ~(size_t)255;
        return p;
    };
    unsigned short* Xb    = (unsigned short*)take((size_t)n64 * 2);  // bf16 x (persistent)
    unsigned short* out1b = (unsigned short*)take((size_t)n64 * 2);  // conv1 out, then conv2 out
    float* partials       = (float*)take((size_t)nbc * 128 * 4);
    unsigned short* P1    = (unsigned short*)take(9 * 8192);
    unsigned short* P2    = (unsigned short*)take(9 * 8192);
    float* ss1            = (float*)take(128 * 4);
    float* ss2            = (float*)take(128 * 4);
    unsigned short* Hb    = (unsigned short*)d_out;  // h (bf16) in d_out's first half;
                                                     // k_final overwrites d_out last, never reads Hb.

    k_cvt_bf16<<<4096, 256, 0, stream>>>(x, Xb, n64 / 4);
    k_pack_w<<<18, 256, 0, stream>>>(w1, P1);
    k_pack_w<<<18, 256, 0, stream>>>(w2, P2);
    k_conv<<<nbc, 512, 0, stream>>>(Xb, nbr, P1, out1b, partials, n);
    k_bnstats<<<64, 256, 0, stream>>>(partials, nbc, n, g1, b1, ss1);
    k_bnrelu<<<2048, 256, 0, stream>>>(out1b, ss1, Hb, n64 / 8);      // h -> d_out (bf16)
    k_conv<<<nbc, 512, 0, stream>>>(Hb, nbr, P2, out1b, partials, n); // conv2 -> out1b
    k_bnstats<<<64, 256, 0, stream>>>(partials, nbc, n, g2, b2, ss2);
    k_final<<<2048, 256, 0, stream>>>(out, Xb, out1b, ss2, n64 / 4);
}

// Round 5
// 296.971 us; speedup vs baseline: 1.3899x; 1.3899x over previous
//
#include <hip/hip_runtime.h>
#include <hip/hip_bf16.h>

typedef __attribute__((ext_vector_type(8))) short bf16x8;
typedef __attribute__((ext_vector_type(4))) float f32x4;

#define EPSV 1e-4f

static __device__ __forceinline__ unsigned short f2bf(float f) {
    unsigned int u = __builtin_bit_cast(unsigned int, f);
    u += 0x7FFFu + ((u >> 16) & 1u);   // round-to-nearest-even
    return (unsigned short)(u >> 16);
}
static __device__ __forceinline__ float bf2f(unsigned short u) {
    unsigned int x = ((unsigned int)u) << 16;
    return __builtin_bit_cast(float, x);
}

// ---------------- x (fp32) -> bf16 ----------------
__global__ __launch_bounds__(256) void k_cvt_bf16(
    const float* __restrict__ in, unsigned short* __restrict__ out, long n4) {
    long i0 = (long)blockIdx.x * 256 + threadIdx.x;
    long stride = (long)gridDim.x * 256;
    const float4* in4 = (const float4*)in;
    ushort4* out4 = (ushort4*)out;
    for (long i = i0; i < n4; i += stride) {
        float4 v = in4[i];
        ushort4 o;
        o.x = f2bf(v.x); o.y = f2bf(v.y); o.z = f2bf(v.z); o.w = f2bf(v.w);
        out4[i] = o;
    }
}

// ---------------- pack W[k][c][d] (fp32) into MFMA-fragment-ordered bf16 ----------------
// frag f = k*8 + s*4 + t ; lane l holds B[k=32s+(l>>4)*8+j][col=16t+(l&15)], j=0..7
__global__ __launch_bounds__(256) void k_pack_w(
    const float* __restrict__ w, unsigned short* __restrict__ P) {
    int tid = blockIdx.x * 256 + threadIdx.x;
    if (tid >= 9 * 8 * 64) return;
    int lane = tid & 63;
    int f = tid >> 6;
    int t = f & 3, s = (f >> 2) & 1, k = f >> 3;
    int d = (t << 4) + (lane & 15);
    int c0 = (s << 5) + ((lane >> 4) << 3);
    bf16x8 v;
#pragma unroll
    for (int j = 0; j < 8; ++j)
        v[j] = (short)f2bf(w[((k * 64) + c0 + j) * 64 + d]);
    ((bf16x8*)P)[tid] = v;
}

// per-fragment BN+ReLU in fp32, back to bf16 (compile-time indexed coefs)
static __device__ __forceinline__ bf16x8 bnrelu8(bf16x8 v, const float* sc, const float* sh) {
    bf16x8 o;
#pragma unroll
    for (int j = 0; j < 8; ++j) {
        float f = bf2f((unsigned short)v[j]);
        f = fmaxf(f * sc[j] + sh[j], 0.f);
        o[j] = (short)f2bf(f);
    }
    return o;
}

// ---------------- gather-GEMM conv: out[n,d] = sum_k sum_c F(X[nbr[n,k]])[c] * W[k,c,d] ----------------
// 512 threads = 8 waves; wave owns 32 rows (two 16-row MFMA tiles); block = 256 rows.
// R2 structure: all 9 offsets' weights staged in LDS once (72 KB), barrier-free k-loop.
// BN=true: F = relu(sc*v+sh) applied per gathered fragment (fuses BN1+ReLU into conv2).
template <bool BN>
__global__ __launch_bounds__(512) void k_conv(
    const unsigned short* __restrict__ Xb,   // bf16 feature table [n][64]
    const int* __restrict__ nbr,             // [n][9]
    const unsigned short* __restrict__ P,    // packed weights (bf16, 9*8 frags)
    const float* __restrict__ ss,            // BN scale/shift (64+64) or null
    unsigned short* __restrict__ outb,       // bf16 out
    float* __restrict__ partials,            // [nblocks][128] sum/sumsq partials
    int n) {
    __shared__ unsigned short sB[36864];     // 72 KB: all 9 offsets, fragment order
    __shared__ float sStat[8][128];
    const int tid = threadIdx.x;
    const int w = tid >> 6, l = tid & 63;
    const int rl = l & 15, ch = l >> 4;
    const int bm = blockIdx.x * 256 + (w << 5);
    const bool valid = bm < n;               // n % 32 == 0 -> wave-uniform
    const int r0 = valid ? bm + rl : 0;
    const int r1 = valid ? bm + 16 + rl : 0;

    {   // stage all weights once (read-only afterwards)
        const float4* src = (const float4*)P;
        float4* dst = (float4*)sB;
#pragma unroll
        for (int i = 0; i < 9; ++i) dst[i * 512 + tid] = src[i * 512 + tid];
    }

    // BN coefficients for this lane's two channel-octets (a0: ch*8.., a1: 32+ch*8..)
    float scA[8], shA[8], scB[8], shB[8];
    if (BN) {
        const int cA = ch << 3, cB = 32 + (ch << 3);
#pragma unroll
        for (int j = 0; j < 8; ++j) {
            scA[j] = ss[cA + j];  shA[j] = ss[64 + cA + j];
            scB[j] = ss[cB + j];  shB[j] = ss[64 + cB + j];
        }
    }

    int idx0[9], idx1[9];
#pragma unroll
    for (int k = 0; k < 9; ++k) {
        idx0[k] = nbr[(long)r0 * 9 + k];
        idx1[k] = nbr[(long)r1 * 9 + k];
    }

    const bf16x8* __restrict__ Xv = (const bf16x8*)Xb;
    f32x4 acc0[4] = {}, acc1[4] = {};

    // A-gather pipeline (depth 2 when BN holds 32 coef VGPRs, else 3)
    constexpr int D = BN ? 2 : 3;
    bf16x8 a[D][4];
#pragma unroll
    for (int d = 0; d < D; ++d) {
        long i0 = (long)idx0[d] * 8, i1 = (long)idx1[d] * 8;
        a[d][0] = Xv[i0 + ch];     a[d][1] = Xv[i0 + 4 + ch];
        a[d][2] = Xv[i1 + ch];     a[d][3] = Xv[i1 + 4 + ch];
    }

    __syncthreads();   // weights staged

    const bf16x8* Bv = (const bf16x8*)sB;
#pragma unroll
    for (int k = 0; k < 9; ++k) {
        const int s = k % D;
        bf16x8 c0 = a[s][0], c1 = a[s][1];
        bf16x8 c2 = a[s][2], c3 = a[s][3];
        if (k < 9 - D) {   // prefetch A for k+D
            long j0 = (long)idx0[k + D] * 8, j1 = (long)idx1[k + D] * 8;
            a[s][0] = Xv[j0 + ch];     a[s][1] = Xv[j0 + 4 + ch];
            a[s][2] = Xv[j1 + ch];     a[s][3] = Xv[j1 + 4 + ch];
        }
        if (BN) {
            c0 = bnrelu8(c0, scA, shA);  c1 = bnrelu8(c1, scB, shB);
            c2 = bnrelu8(c2, scA, shA);  c3 = bnrelu8(c3, scB, shB);
        }
#pragma unroll
        for (int t = 0; t < 4; ++t) {
            bf16x8 b0 = Bv[(k * 8 + t) * 64 + l];
            bf16x8 b1 = Bv[(k * 8 + 4 + t) * 64 + l];
            acc0[t] = __builtin_amdgcn_mfma_f32_16x16x32_bf16(c0, b0, acc0[t], 0, 0, 0);
            acc0[t] = __builtin_amdgcn_mfma_f32_16x16x32_bf16(c1, b1, acc0[t], 0, 0, 0);
            acc1[t] = __builtin_amdgcn_mfma_f32_16x16x32_bf16(c2, b0, acc1[t], 0, 0, 0);
            acc1[t] = __builtin_amdgcn_mfma_f32_16x16x32_bf16(c3, b1, acc1[t], 0, 0, 0);
        }
    }

    // C/D layout: col = 16t + rl, row = ch*4 + reg  (tile1 rows +16)
    if (valid) {
#pragma unroll
        for (int t = 0; t < 4; ++t)
#pragma unroll
            for (int r = 0; r < 4; ++r) {
                outb[(long)(bm + (ch << 2) + r) * 64 + (t << 4) + rl] = f2bf(acc0[t][r]);
                outb[(long)(bm + 16 + (ch << 2) + r) * 64 + (t << 4) + rl] = f2bf(acc1[t][r]);
            }
    }

    // per-block BN stat partials (exact fp32 from accumulators)
    float sa[4], sq[4];
#pragma unroll
    for (int t = 0; t < 4; ++t) {
        float s = 0.f, q = 0.f;
#pragma unroll
        for (int r = 0; r < 4; ++r) {
            s += acc0[t][r] + acc1[t][r];
            q += acc0[t][r] * acc0[t][r] + acc1[t][r] * acc1[t][r];
        }
        s += __shfl_xor(s, 16); s += __shfl_xor(s, 32);
        q += __shfl_xor(q, 16); q += __shfl_xor(q, 32);
        sa[t] = valid ? s : 0.f;
        sq[t] = valid ? q : 0.f;
    }
    if (l < 16) {
#pragma unroll
        for (int t = 0; t < 4; ++t) {
            sStat[w][(t << 4) + l] = sa[t];
            sStat[w][64 + (t << 4) + l] = sq[t];
        }
    }
    __syncthreads();
    if (tid < 128) {
        float s = 0.f;
#pragma unroll
        for (int i = 0; i < 8; ++i) s += sStat[i][tid];
        partials[(long)blockIdx.x * 128 + tid] = s;
    }
}

// ---------------- reduce partials -> scale/shift ----------------
__global__ __launch_bounds__(256) void k_bnstats(
    const float* __restrict__ partials, int nb, int n,
    const float* __restrict__ gamma, const float* __restrict__ beta,
    float* __restrict__ ss) {
    const int d = blockIdx.x;     // 0..63
    const int tid = threadIdx.x;
    float s = 0.f, q = 0.f;
    for (int i = tid; i < nb; i += 256) {
        s += partials[(long)i * 128 + d];
        q += partials[(long)i * 128 + 64 + d];
    }
#pragma unroll
    for (int off = 32; off > 0; off >>= 1) {
        s += __shfl_xor(s, off);
        q += __shfl_xor(q, off);
    }
    __shared__ float rs_[4], rq_[4];
    if ((tid & 63) == 0) { rs_[tid >> 6] = s; rq_[tid >> 6] = q; }
    __syncthreads();
    if (tid == 0) {
        s = rs_[0] + rs_[1] + rs_[2] + rs_[3];
        q = rq_[0] + rq_[1] + rq_[2] + rq_[3];
        float mu = s / (float)n;
        float var = q / (float)n - mu * mu;
        float rsg = rsqrtf(var + EPSV);
        float sc = rsg * gamma[d];
        ss[d] = sc;
        ss[64 + d] = beta[d] - mu * sc;
    }
}

// ---------------- BN2 + residual + ReLU: out = relu(bn2(conv2_bf16) + x_bf16) ----------------
__global__ __launch_bounds__(256) void k_final(
    float* __restrict__ out, const unsigned short* __restrict__ xb,
    const unsigned short* __restrict__ c2, const float* __restrict__ ss, long n4) {
    __shared__ float ssc[64], ssh[64];
    if (threadIdx.x < 64) { ssc[threadIdx.x] = ss[threadIdx.x]; ssh[threadIdx.x] = ss[64 + threadIdx.x]; }
    __syncthreads();
    long i0 = (long)blockIdx.x * 256 + threadIdx.x;
    long stride = (long)gridDim.x * 256;
    const ushort4* x4 = (const ushort4*)xb;
    const ushort4* c4 = (const ushort4*)c2;
    float4* o4 = (float4*)out;
    for (long i = i0; i < n4; i += stride) {
        ushort4 v = c4[i];
        ushort4 xv = x4[i];
        int db = (int)((i & 15) << 2);
        float4 r;
        r.x = fmaxf(bf2f(v.x) * ssc[db + 0] + ssh[db + 0] + bf2f(xv.x), 0.f);
        r.y = fmaxf(bf2f(v.y) * ssc[db + 1] + ssh[db + 1] + bf2f(xv.y), 0.f);
        r.z = fmaxf(bf2f(v.z) * ssc[db + 2] + ssh[db + 2] + bf2f(xv.z), 0.f);
        r.w = fmaxf(bf2f(v.w) * ssc[db + 3] + ssh[db + 3] + bf2f(xv.w), 0.f);
        o4[i] = r;
    }
}

extern "C" void kernel_launch(void* const* d_in, const int* in_sizes, int n_in,
                              void* d_out, int out_size, void* d_ws, size_t ws_size,
                              hipStream_t stream) {
    const float* x  = (const float*)d_in[0];
    const int* nbr  = (const int*)d_in[1];
    const float* w1 = (const float*)d_in[2];
    const float* w2 = (const float*)d_in[3];
    const float* g1 = (const float*)d_in[4];
    const float* b1 = (const float*)d_in[5];
    const float* g2 = (const float*)d_in[6];
    const float* b2 = (const float*)d_in[7];
    float* out = (float*)d_out;

    const int n = in_sizes[0] / 64;          // 500000
    const int nbc = (n + 255) / 256;         // conv blocks (256 rows each)
    const long n64 = (long)n * 64;

    char* ws = (char*)d_ws;
    size_t off = 0;
    auto take = [&](size_t bytes) {
        char* p = ws + off;
        off = (off + bytes + 255) & ~(size_t)255;
        return p;
    };
    unsigned short* Xb    = (unsigned short*)take((size_t)n64 * 2);  // bf16 x (persistent)
    unsigned short* c2raw = (unsigned short*)take((size_t)n64 * 2);  // conv2 raw output (bf16)
    float* partials       = (float*)take((size_t)nbc * 128 * 4);
    unsigned short* P1    = (unsigned short*)take(9 * 8192);
    unsigned short* P2    = (unsigned short*)take(9 * 8192);
    float* ss1            = (float*)take(128 * 4);
    float* ss2            = (float*)take(128 * 4);
    unsigned short* c1raw = (unsigned short*)d_out;  // conv1 raw output (bf16) parks in d_out;
                                                     // conv2 reads it fully before k_final
                                                     // overwrites d_out (kernel-level separation).

    k_cvt_bf16<<<4096, 256, 0, stream>>>(x, Xb, n64 / 4);
    k_pack_w<<<18, 256, 0, stream>>>(w1, P1);
    k_pack_w<<<18, 256, 0, stream>>>(w2, P2);
    k_conv<false><<<nbc, 512, 0, stream>>>(Xb, nbr, P1, nullptr, c1raw, partials, n);
    k_bnstats<<<64, 256, 0, stream>>>(partials, nbc, n, g1, b1, ss1);
    k_conv<true><<<nbc, 512, 0, stream>>>(c1raw, nbr, P2, ss1, c2raw, partials, n);
    k_bnstats<<<64, 256, 0, stream>>>(partials, nbc, n, g2, b2, ss2);
    k_final<<<2048, 256, 0, stream>>>(out, Xb, c2raw, ss2, n64 / 4);
}